// Round 1
// baseline (45.388 us; speedup 1.0000x reference)
//
#include <hip/hip_runtime.h>

// Elementwise: y = x*w + b (w,b broadcast over batch); out = y if 0 < y <= 1 else 0.
// x: [8192, 4096] f32, w: [4096] f32, b: [4096] f32, out: [8192, 4096] f32.
// Memory-bound: ~268 MB HBM traffic -> target ~45 us at 6.3 TB/s.

__global__ void capped_relu_kernel(const float4* __restrict__ x4,
                                   const float*  __restrict__ w,
                                   const float*  __restrict__ b,
                                   float4* __restrict__ out4,
                                   long n4) {
    const long stride = (long)gridDim.x * blockDim.x;
    for (long i = (long)blockIdx.x * blockDim.x + threadIdx.x; i < n4; i += stride) {
        float4 v = x4[i];
        // column of first element in this float4; INPUT_SIZE = 4096
        const int c = (int)((i << 2) & 4095);
        const float4 wv = *reinterpret_cast<const float4*>(&w[c]);
        const float4 bv = *reinterpret_cast<const float4*>(&b[c]);
        float4 y;
        y.x = v.x * wv.x + bv.x;
        y.y = v.y * wv.y + bv.y;
        y.z = v.z * wv.z + bv.z;
        y.w = v.w * wv.w + bv.w;
        y.x = (y.x > 0.0f && y.x <= 1.0f) ? y.x : 0.0f;
        y.y = (y.y > 0.0f && y.y <= 1.0f) ? y.y : 0.0f;
        y.z = (y.z > 0.0f && y.z <= 1.0f) ? y.z : 0.0f;
        y.w = (y.w > 0.0f && y.w <= 1.0f) ? y.w : 0.0f;
        out4[i] = y;
    }
}

extern "C" void kernel_launch(void* const* d_in, const int* in_sizes, int n_in,
                              void* d_out, int out_size, void* d_ws, size_t ws_size,
                              hipStream_t stream) {
    const float* x = (const float*)d_in[0];
    const float* w = (const float*)d_in[1];
    const float* b = (const float*)d_in[2];
    float* out = (float*)d_out;

    const long n  = (long)out_size;        // 8192 * 4096
    const long n4 = n >> 2;                // float4 count (n is a multiple of 4)

    const int block = 256;
    long blocks_needed = (n4 + block - 1) / block;
    int grid = (int)((blocks_needed < 2048) ? blocks_needed : 2048);

    capped_relu_kernel<<<grid, block, 0, stream>>>(
        (const float4*)x, w, b, (float4*)out, n4);
}